// Round 1
// 460.403 us; speedup vs baseline: 1.0222x; 1.0222x over previous
//
#include <hip/hip_runtime.h>

// Problem constants (from reference)
constexpr int Bn = 4096;
constexpr int Tn = 200;
constexpr int Dn = 64;
constexpr int Pn = 2;

constexpr int THETA_BLOCKS = 512;
constexpr int N_PARTIALS   = Bn + THETA_BLOCKS;   // 4608

typedef float f4 __attribute__((ext_vector_type(4)));

// ---- block-wide reduce -> one value in thread 0 ----
__device__ __forceinline__ float block_reduce(float v) {
#pragma unroll
    for (int off = 32; off > 0; off >>= 1)
        v += __shfl_down(v, off, 64);
    __shared__ float smem[4];
    const int lane = threadIdx.x & 63;
    const int wave = threadIdx.x >> 6;
    if (lane == 0) smem[wave] = v;
    __syncthreads();
    float s = 0.f;
    if (threadIdx.x == 0) {
        const int nw = blockDim.x >> 6;
        for (int i = 0; i < nw; ++i) s += smem[i];
    }
    return s;
}

// ---- fused kernel ----
// blocks [0, Bn):          term 1 (step_ahead_cov_reg), one block per individual b.
//                          Only active quads are visited: (len-1)*16 loop trips,
//                          lengths[b] read once (scalar), scale hoisted out of loop.
// blocks [Bn, Bn+512):     terms 2+3 (theta_drift + global_diff), grid-stride over pp.
__global__ __launch_bounds__(256) void main_kernel(
        const float* __restrict__ cov,
        const float* __restrict__ preds,
        const int*   __restrict__ lengths,
        const float* __restrict__ pp,
        const float* __restrict__ theta,
        float*       __restrict__ partials) {
    if (blockIdx.x < (unsigned)Bn) {
        const int b   = blockIdx.x;
        const int len = lengths[b];                       // block-uniform -> scalar load
        float acc = 0.f;
        if (len > 1) {
            const unsigned nq = (unsigned)(len - 1) * (Dn / 4);   // active quads only
            const float* __restrict__ pbase = preds + (size_t)b * (Tn - 1) * Dn;
            const float* __restrict__ cbase = cov   + (size_t)b * Tn * (Dn + 1)
                                              + (Dn + 1) + 1;     // row t+1, col d+1
            for (unsigned r = threadIdx.x; r < nq; r += 256) {
                const unsigned t = r >> 4;                // 0..len-2
                const unsigned d = (r & 15u) << 2;        // 0,4,..,60
                const f4 p = __builtin_nontemporal_load(
                    reinterpret_cast<const f4*>(pbase + (size_t)t * Dn + d));
                const float* c = cbase + (size_t)t * (Dn + 1) + d;
                const float d0 = c[0] - p.x;
                const float d1 = c[1] - p.y;
                const float d2 = c[2] - p.z;
                const float d3 = c[3] - p.w;
                acc += d0 * d0 + d1 * d1 + d2 * d2 + d3 * d3;
            }
            acc *= 1.0f / ((float)Dn * (float)Bn * (float)(len - 1));
        }
        const float s = block_reduce(acc);
        if (threadIdx.x == 0) partials[b] = s;
    } else {
        const float r0 = 1.0f / theta[0];
        const float r1 = 1.0f / theta[1];
        const float gw = 0.01f / ((float)Bn * (float)Tn * (float)Pn);
        const float dw = 0.1f  / ((float)Bn * (float)(Tn - 1) * (float)Pn);
        constexpr unsigned total = (unsigned)Bn * Tn;     // 819,200 (b,t) pairs
        float acc = 0.f;
        const unsigned stride = THETA_BLOCKS * 256;
        for (unsigned i = (blockIdx.x - Bn) * 256 + threadIdx.x; i < total; i += stride) {
            const unsigned t = i % (unsigned)Tn;
            const float2 x = *reinterpret_cast<const float2*>(pp + (size_t)i * 2);
            const float g0 = x.x * r0 - 1.0f;
            const float g1 = x.y * r1 - 1.0f;
            acc += (g0 * g0 + g1 * g1) * gw;
            if (t < Tn - 1) {                             // drift vs next step
                const float2 y = *reinterpret_cast<const float2*>(pp + (size_t)i * 2 + 2);
                const float e0 = x.x - y.x;
                const float e1 = x.y - y.y;
                acc += (e0 * e0 + e1 * e1) * dw;
            }
        }
        const float s = block_reduce(acc);
        if (threadIdx.x == 0) partials[blockIdx.x] = s;   // slots [Bn, Bn+512)
    }
}

// ---- finisher: sum 4608 partials, write scalar output ----
__global__ void final_kernel(const float* __restrict__ partials,
                             float* __restrict__ out) {
    float acc = 0.f;
    for (int i = threadIdx.x; i < N_PARTIALS; i += blockDim.x)
        acc += partials[i];
    const float s = block_reduce(acc);
    if (threadIdx.x == 0) out[0] = s;
}

extern "C" void kernel_launch(void* const* d_in, const int* in_sizes, int n_in,
                              void* d_out, int out_size, void* d_ws, size_t ws_size,
                              hipStream_t stream) {
    const float* theta   = (const float*)d_in[0];  // [P]
    const float* pp      = (const float*)d_in[1];  // [B,T,P]
    // d_in[2] = hidden_states — unused by the reference
    const float* preds   = (const float*)d_in[3];  // [B,T-1,D]
    const float* cov     = (const float*)d_in[4];  // [B,T,D+1]
    const int*   lengths = (const int*)d_in[5];    // [B]
    float* out      = (float*)d_out;
    float* partials = (float*)d_ws;                // 4608 floats, written before read

    main_kernel<<<Bn + THETA_BLOCKS, 256, 0, stream>>>(cov, preds, lengths, pp, theta, partials);
    final_kernel<<<1, 256, 0, stream>>>(partials, out);
}

// Round 2
// 460.019 us; speedup vs baseline: 1.0230x; 1.0008x over previous
//
#include <hip/hip_runtime.h>

// Problem constants (from reference)
constexpr int Bn = 4096;
constexpr int Tn = 200;
constexpr int Dn = 64;
constexpr int Pn = 2;

constexpr int THETA_BLOCKS = 512;
constexpr int N_PARTIALS   = Bn + THETA_BLOCKS;   // 4608

typedef float f4 __attribute__((ext_vector_type(4)));

// ---- block-wide reduce -> one value in thread 0 ----
__device__ __forceinline__ float block_reduce(float v) {
#pragma unroll
    for (int off = 32; off > 0; off >>= 1)
        v += __shfl_down(v, off, 64);
    __shared__ float smem[4];
    const int lane = threadIdx.x & 63;
    const int wave = threadIdx.x >> 6;
    if (lane == 0) smem[wave] = v;
    __syncthreads();
    float s = 0.f;
    if (threadIdx.x == 0) {
        const int nw = blockDim.x >> 6;
        for (int i = 0; i < nw; ++i) s += smem[i];
    }
    return s;
}

// Unaligned 16B load: clang sees align=4 and (gfx9+ unaligned-access-mode on)
// emits a single global_load_dwordx4 at the 4B-aligned address.
__device__ __forceinline__ f4 load_f4_unaligned(const float* p) {
    f4 v;
    __builtin_memcpy(&v, p, 16);
    return v;
}

// ---- fused kernel ----
// blocks [0, Bn):       term 1 (step_ahead_cov_reg), one block per individual b.
//                       Only active quads visited; lengths[b] read once (scalar);
//                       1/(len-1) scale hoisted out of the loop.
// blocks [Bn, Bn+512):  terms 2+3 (theta_drift + global_diff), grid-stride over pp.
__global__ __launch_bounds__(256) void main_kernel(
        const float* __restrict__ cov,
        const float* __restrict__ preds,
        const int*   __restrict__ lengths,
        const float* __restrict__ pp,
        const float* __restrict__ theta,
        float*       __restrict__ partials) {
    if (blockIdx.x < (unsigned)Bn) {
        const int b   = blockIdx.x;
        const int len = lengths[b];                       // block-uniform -> scalar load
        float acc = 0.f;
        if (len > 1) {
            const unsigned nq = (unsigned)(len - 1) * (Dn / 4);   // active quads only
            const float* __restrict__ pbase = preds + (size_t)b * (Tn - 1) * Dn;
            const float* __restrict__ cbase = cov   + (size_t)b * Tn * (Dn + 1)
                                              + (Dn + 1) + 1;     // row t+1, col d+1
            for (unsigned r = threadIdx.x; r < nq; r += 256) {
                const unsigned t = r >> 4;                // 0..len-2
                const unsigned d = (r & 15u) << 2;        // 0,4,..,60
                const f4 p = __builtin_nontemporal_load(
                    reinterpret_cast<const f4*>(pbase + (size_t)t * Dn + d));
                const f4 c = load_f4_unaligned(cbase + (size_t)t * (Dn + 1) + d);
                const float d0 = c.x - p.x;
                const float d1 = c.y - p.y;
                const float d2 = c.z - p.z;
                const float d3 = c.w - p.w;
                acc += d0 * d0 + d1 * d1 + d2 * d2 + d3 * d3;
            }
            acc *= 1.0f / ((float)Dn * (float)Bn * (float)(len - 1));
        }
        const float s = block_reduce(acc);
        if (threadIdx.x == 0) partials[b] = s;
    } else {
        const float r0 = 1.0f / theta[0];
        const float r1 = 1.0f / theta[1];
        const float gw = 0.01f / ((float)Bn * (float)Tn * (float)Pn);
        const float dw = 0.1f  / ((float)Bn * (float)(Tn - 1) * (float)Pn);
        constexpr unsigned total = (unsigned)Bn * Tn;     // 819,200 (b,t) pairs
        float acc = 0.f;
        const unsigned stride = THETA_BLOCKS * 256;
        for (unsigned i = (blockIdx.x - Bn) * 256 + threadIdx.x; i < total; i += stride) {
            const unsigned t = i % (unsigned)Tn;
            const float2 x = *reinterpret_cast<const float2*>(pp + (size_t)i * 2);
            const float g0 = x.x * r0 - 1.0f;
            const float g1 = x.y * r1 - 1.0f;
            acc += (g0 * g0 + g1 * g1) * gw;
            if (t < Tn - 1) {                             // drift vs next step
                const float2 y = *reinterpret_cast<const float2*>(pp + (size_t)i * 2 + 2);
                const float e0 = x.x - y.x;
                const float e1 = x.y - y.y;
                acc += (e0 * e0 + e1 * e1) * dw;
            }
        }
        const float s = block_reduce(acc);
        if (threadIdx.x == 0) partials[blockIdx.x] = s;   // slots [Bn, Bn+512)
    }
}

// ---- finisher: sum 4608 partials, write scalar output ----
__global__ void final_kernel(const float* __restrict__ partials,
                             float* __restrict__ out) {
    float acc = 0.f;
    for (int i = threadIdx.x; i < N_PARTIALS; i += blockDim.x)
        acc += partials[i];
    const float s = block_reduce(acc);
    if (threadIdx.x == 0) out[0] = s;
}

extern "C" void kernel_launch(void* const* d_in, const int* in_sizes, int n_in,
                              void* d_out, int out_size, void* d_ws, size_t ws_size,
                              hipStream_t stream) {
    const float* theta   = (const float*)d_in[0];  // [P]
    const float* pp      = (const float*)d_in[1];  // [B,T,P]
    // d_in[2] = hidden_states — unused by the reference
    const float* preds   = (const float*)d_in[3];  // [B,T-1,D]
    const float* cov     = (const float*)d_in[4];  // [B,T,D+1]
    const int*   lengths = (const int*)d_in[5];    // [B]
    float* out      = (float*)d_out;
    float* partials = (float*)d_ws;                // 4608 floats, written before read

    main_kernel<<<Bn + THETA_BLOCKS, 256, 0, stream>>>(cov, preds, lengths, pp, theta, partials);
    final_kernel<<<1, 256, 0, stream>>>(partials, out);
}